// Round 12
// baseline (173.215 us; speedup 1.0000x reference)
//
#include <hip/hip_runtime.h>

// LeakySNN fused: out[b] = b2 + sum_h spksum(x1[b,h]) * W2[h]
// R12 = R11 + two latency-bound levers (no saturated pipe at R11: MFMA 33%,
//   VALU 47%, HBM 7%, occupancy 3 blocks/CU):
//   (1) __launch_bounds__(256,4): 64 VGPR + 64 AGPR = 128 = 512/4 exactly ->
//       4 blocks/CU, +33% TLP for the fragment-direct GEMM's L2 latency.
//   (2) hi|lo granules interleaved in ONE array (32 B/lane contiguous pair
//       loads, half the base pointers / address setup).
//   Epilogue stays R11: LDS binary search (VALU-light), stride-33 bpl.
//   b1 folded into breakpoints (exact). Fallback unchanged.

#define NI 256
#define NH 1024
#define NSTEPS 25
#define BT 128
#define BK 32
#define NTILES (NI / BK)
#define BPS 33        // bpl row stride (floats); 33 % 32 == 1 -> bank = hl+k
#define RW 40         // fallback (R6) LDS row width in halfs

typedef _Float16 half8 __attribute__((ext_vector_type(8)));
typedef _Float16 half4 __attribute__((ext_vector_type(4)));
typedef float float4v __attribute__((ext_vector_type(4)));

__device__ __forceinline__ unsigned f2k(float f) {
    unsigned u = __float_as_uint(f);
    return (u >> 31) ? ~u : (u | 0x80000000u);
}
__device__ __forceinline__ float k2f(unsigned k) {
    unsigned u = (k & 0x80000000u) ? (k & 0x7FFFFFFFu) : ~k;
    return __uint_as_float(u);
}

// 25-step LIF count, exact reference-matching arithmetic (R4/R6).
__device__ __forceinline__ int lif_count(float x1, float beta, float th) {
    float mem = 0.f;
    float spk = (0.f > th) ? 1.f : 0.f;
    int c = 0;
#pragma unroll
    for (int t = 0; t < NSTEPS; t++) {
        mem = fmaf(spk, -th, fmaf(beta, mem, x1));
        spk = (mem > th) ? 1.f : 0.f;
        c += (mem > th);
    }
    return c;
}

__device__ __forceinline__ void split8(const float* src, half8* hi, half8* lo) {
    float4v a = *(const float4v*)src;
    float4v b = *(const float4v*)(src + 4);
#pragma unroll
    for (int e = 0; e < 4; e++) {
        _Float16 h = (_Float16)a[e];
        (*hi)[e] = h;
        (*lo)[e] = (_Float16)(a[e] - (float)h);
        h = (_Float16)b[e];
        (*hi)[e + 4] = h;
        (*lo)[e + 4] = (_Float16)(b[e] - (float)h);
    }
}

// ===================== fast path =====================

// Granule-pair layout (16 halfs = hi8|lo8 of one MFMA k-chunk of one row):
//   G = band*4096 + kt*512 + r8*64 + quad*16 + col   (pair index = 2G, 2G+1)
//   holds src[row = band*128 + r8*16 + col][k = kt*32 + quad*8 .. +8]
__global__ __launch_bounds__(256) void snn_prep(
    const float* __restrict__ x, const float* __restrict__ W1,
    const float* __restrict__ thr, const float* __restrict__ betap,
    const float* __restrict__ b1, const float* __restrict__ b2,
    float* __restrict__ out, float* __restrict__ bp,
    _Float16* __restrict__ wsp, _Float16* __restrict__ xsp, int B)
{
    const int tid = threadIdx.x;
    const int XB = B / 8;            // x granules / 256
    int bid = blockIdx.x;

    if (bid < XB) {                  // ---- x split ----
        const int G = bid * 256 + tid;
        const int band = G >> 12;
        const int rem = G & 4095;
        const int kt = rem >> 9;
        const int rem2 = rem & 511;
        const int r8 = rem2 >> 6, quad = (rem2 >> 4) & 3, col = rem2 & 15;
        const float* src = x + (size_t)(band * 128 + r8 * 16 + col) * NI + kt * 32 + quad * 8;
        half8 hi, lo;
        split8(src, &hi, &lo);
        ((half8*)xsp)[2 * (size_t)G]     = hi;
        ((half8*)xsp)[2 * (size_t)G + 1] = lo;
        return;
    }
    bid -= XB;
    if (bid < 128) {                 // ---- W1 split ----
        const int G = bid * 256 + tid;   // < 32768
        const int band = G >> 12;
        const int rem = G & 4095;
        const int kt = rem >> 9;
        const int rem2 = rem & 511;
        const int r8 = rem2 >> 6, quad = (rem2 >> 4) & 3, col = rem2 & 15;
        const float* src = W1 + (size_t)(band * 128 + r8 * 16 + col) * NI + kt * 32 + quad * 8;
        half8 hi, lo;
        split8(src, &hi, &lo);
        ((half8*)wsp)[2 * (size_t)G]     = hi;
        ((half8*)wsp)[2 * (size_t)G + 1] = lo;
        return;
    }
    bid -= 128;
    if (bid < 100) {                 // ---- breakpoints, b1 folded in ----
        const int idx = bid * 256 + tid;     // exactly 25600
        const int h = idx / NSTEPS;
        const int k = idx % NSTEPS + 1;      // target count 1..25
        const float th = thr[h];
        const float bj = b1[h];
        float beta = betap[0];
        beta = beta < 0.f ? 0.f : (beta > 1.f ? 1.f : beta);
        // c'_k = smallest float a with lif_count(fl(a + bj)) >= k.
        // Then (acc >= c'_k) <=> count(fl(acc+bj)) >= k: exact (monotone).
        unsigned lo = f2k(-3.0e38f), hi = f2k(3.0e38f);
        float res;
        if (lif_count(k2f(hi) + bj, beta, th) < k) {
            res = 3.0e38f;
        } else if (lif_count(k2f(lo) + bj, beta, th) >= k) {
            res = -3.0e38f;
        } else {
#pragma unroll 1
            for (int it = 0; it < 32; it++) {
                unsigned mid = lo + ((hi - lo) >> 1);
                if (lif_count(k2f(mid) + bj, beta, th) >= k) hi = mid; else lo = mid;
            }
            res = k2f(hi);
        }
        bp[h * 32 + (k - 1)] = res;   // [h][32] layout, coalesced staging
        return;
    }
    bid -= 100;
    {                                // ---- out init ----
        const int i = bid * 256 + tid;
        if (i < B) out[i] = b2[0];
    }
}

__global__ __launch_bounds__(256, 4) void snn_main_fast(
    const _Float16* __restrict__ xsp, const _Float16* __restrict__ wsp,
    const float* __restrict__ W2, const float* __restrict__ bp,
    float* __restrict__ out)
{
    __shared__ float smem[128 * BPS];  // 16.9 KB: bpl[hl][33], later red[128][33]

    const int tid  = threadIdx.x;
    const int w    = tid >> 6;
    const int lane = tid & 63;
    const int col  = lane & 15;
    const int quad = lane >> 4;
    const int wbb  = (w >> 1) * 64;
    const int whh  = (w & 1) * 64;
    const int bband = blockIdx.x;
    const int hband = blockIdx.y;
    const int b0 = bband * BT;
    const int h0 = hband * BT;
    const int loff = quad * 16 + col;

    const half8* xs = (const half8*)xsp + (size_t)bband * 8192 + 2 * ((w >> 1) * 256 + loff);
    const half8* ws = (const half8*)wsp + (size_t)hband * 8192 + 2 * ((w & 1) * 256 + loff);

    // stage breakpoints early (overlaps GEMM; barrier only before use).
    // bpl[hl*33 + k] = c_{k+1} for k<25, +inf pad for 25..31.
    float* bpl = smem;
#pragma unroll
    for (int rep = 0; rep < 16; rep++) {
        const int n = tid + 256 * rep;       // 4096 = 128 rows x 32 k
        const int hl = n >> 5, k = n & 31;
        const float v = bp[(h0 + hl) * 32 + k];
        bpl[hl * BPS + k] = (k < NSTEPS) ? v : 3.0e38f;
    }

    float4v acc[4][4];
#pragma unroll
    for (int i = 0; i < 4; i++)
#pragma unroll
        for (int j = 0; j < 4; j++) acc[i][j] = (float4v){0.f, 0.f, 0.f, 0.f};

    // ---- GEMM: fragment-direct interleaved loads, compiler-scheduled ----
#pragma unroll 2
    for (int kt = 0; kt < NTILES; kt++) {
        const int gi = kt * 1024;          // half8 pairs per k-tile
        half8 ah[4], al[4], bh[4], bl[4];
#pragma unroll
        for (int i = 0; i < 4; i++) {
            ah[i] = xs[gi + i * 128];
            al[i] = xs[gi + i * 128 + 1];
        }
#pragma unroll
        for (int j = 0; j < 4; j++) {
            bh[j] = ws[gi + j * 128];
            bl[j] = ws[gi + j * 128 + 1];
        }
#pragma unroll
        for (int j = 0; j < 4; j++)
#pragma unroll
            for (int i = 0; i < 4; i++) {
                acc[i][j] = __builtin_amdgcn_mfma_f32_16x16x32_f16(ah[i], bh[j], acc[i][j], 0, 0, 0);
                acc[i][j] = __builtin_amdgcn_mfma_f32_16x16x32_f16(ah[i], bl[j], acc[i][j], 0, 0, 0);
                acc[i][j] = __builtin_amdgcn_mfma_f32_16x16x32_f16(al[i], bh[j], acc[i][j], 0, 0, 0);
            }
    }

    __syncthreads();   // bpl staged; all waves past GEMM loads

    // ---- count via 5-level branch-free binary search on the LDS pipe ----
    // m = max{k : x1 >= c_k}; c_k sorted nondecreasing, padded to 31 w/ +inf.
    float part[16];
#pragma unroll
    for (int e = 0; e < 16; e++) part[e] = 0.f;

#pragma unroll
    for (int j = 0; j < 4; j++) {
        const int hl = whh + 16 * j + col;
        const float w2 = W2[h0 + hl];
        const float* pj = bpl + hl * BPS;
        float x1[16];
        int mo[16];
#pragma unroll
        for (int e = 0; e < 16; e++) {
            x1[e] = acc[e >> 2][j][e & 3];
            mo[e] = 0;
        }
#pragma unroll
        for (int bstep = 16; bstep >= 1; bstep >>= 1) {
#pragma unroll
            for (int e = 0; e < 16; e++) {
                const float c = pj[mo[e] + bstep - 1];   // row m+bstep-1 = c_{m+bstep}
                mo[e] += (x1[e] >= c) ? bstep : 0;
            }
        }
#pragma unroll
        for (int e = 0; e < 16; e++)
            part[e] = fmaf((float)mo[e], w2, part[e]);
    }

    // ---- block reduction, one atomic per b-row ----
    __syncthreads();                   // bpl dead
    float* red = smem;                 // 128 x 33
#pragma unroll
    for (int e = 0; e < 16; e++) {
        const int row = wbb + 16 * (e >> 2) + 4 * quad + (e & 3);
        red[row * 33 + (w & 1) * 16 + col] = part[e];
    }
    __syncthreads();
    if (tid < BT) {
        float s = 0.f;
#pragma unroll
        for (int c2 = 0; c2 < 32; c2++) s += red[tid * 33 + c2];
        atomicAdd(&out[b0 + tid], s);
    }
}

// ===================== fallback path (R6-style, ws too small) =====================

__global__ __launch_bounds__(256) void snn_prep_small(
    const float* __restrict__ thr, const float* __restrict__ betap,
    const float* __restrict__ b2, float* __restrict__ out,
    float* __restrict__ bp, int B)
{
    const int tid = threadIdx.x;
    int bid = blockIdx.x;
    if (bid < 100) {
        const int idx = bid * 256 + tid;
        const int h = idx / NSTEPS;
        const int k = idx % NSTEPS + 1;
        const float th = thr[h];
        float beta = betap[0];
        beta = beta < 0.f ? 0.f : (beta > 1.f ? 1.f : beta);
        unsigned lo = f2k(-3.0e38f), hi = f2k(3.0e38f);
        float res;
        if (lif_count(k2f(hi), beta, th) < k) res = 3.0e38f;
        else if (lif_count(k2f(lo), beta, th) >= k) res = -3.0e38f;
        else {
#pragma unroll 1
            for (int it = 0; it < 32; it++) {
                unsigned mid = lo + ((hi - lo) >> 1);
                if (lif_count(k2f(mid), beta, th) >= k) hi = mid; else lo = mid;
            }
            res = k2f(hi);
        }
        bp[(k - 1) * NH + h] = res;
        return;
    }
    bid -= 100;
    const int i = bid * 256 + tid;
    if (i < B) out[i] = b2[0];
}

__global__ __launch_bounds__(256, 3) void snn_main_fb(
    const float* __restrict__ x, const float* __restrict__ W1,
    const float* __restrict__ b1, const float* __restrict__ W2,
    const float* __restrict__ bp, float* __restrict__ out)
{
    __shared__ __align__(16) _Float16 lds[4 * BT * RW];
    _Float16* xh = lds;
    _Float16* xl = lds + BT * RW;
    _Float16* wh = lds + 2 * BT * RW;
    _Float16* wl = lds + 3 * BT * RW;

    const int tid  = threadIdx.x;
    const int w    = tid >> 6;
    const int lane = tid & 63;
    const int col  = lane & 15;
    const int quad = lane >> 4;
    const int wbb  = (w >> 1) * 64;
    const int whh  = (w & 1) * 64;
    const int b0 = blockIdx.x * BT;
    const int h0 = blockIdx.y * BT;

    float4v acc[4][4];
#pragma unroll
    for (int i = 0; i < 4; i++)
#pragma unroll
        for (int j = 0; j < 4; j++) acc[i][j] = (float4v){0.f, 0.f, 0.f, 0.f};

    const int r0 = tid >> 3;
    const int c4 = tid & 7;
    const float* xrow = x + (size_t)(b0 + r0) * NI + 4 * c4;
    const float* wrow = W1 + (size_t)(h0 + r0) * NI + 4 * c4;

    for (int kt = 0; kt < NTILES; kt++) {
        const int ko = kt * BK;
        float4v vx[4], vw[4];
#pragma unroll
        for (int p = 0; p < 4; p++) {
            vx[p] = *(const float4v*)(xrow + (size_t)(32 * p) * NI + ko);
            vw[p] = *(const float4v*)(wrow + (size_t)(32 * p) * NI + ko);
        }
        __syncthreads();
#pragma unroll
        for (int p = 0; p < 4; p++) {
            const int row = r0 + 32 * p;
            half4 hx, lx, hw, lw;
#pragma unroll
            for (int q = 0; q < 4; q++) {
                float v = vx[p][q];
                _Float16 h = (_Float16)v;
                hx[q] = h;
                lx[q] = (_Float16)(v - (float)h);
                v = vw[p][q];
                h = (_Float16)v;
                hw[q] = h;
                lw[q] = (_Float16)(v - (float)h);
            }
            *(half4*)&xh[row * RW + 4 * c4] = hx;
            *(half4*)&xl[row * RW + 4 * c4] = lx;
            *(half4*)&wh[row * RW + 4 * c4] = hw;
            *(half4*)&wl[row * RW + 4 * c4] = lw;
        }
        __syncthreads();

        half8 ah[4], al[4];
#pragma unroll
        for (int i = 0; i < 4; i++) {
            ah[i] = *(const half8*)&xh[(wbb + 16 * i + col) * RW + 8 * quad];
            al[i] = *(const half8*)&xl[(wbb + 16 * i + col) * RW + 8 * quad];
        }
#pragma unroll
        for (int j = 0; j < 4; j++) {
            half8 bh = *(const half8*)&wh[(whh + 16 * j + col) * RW + 8 * quad];
            half8 bl = *(const half8*)&wl[(whh + 16 * j + col) * RW + 8 * quad];
#pragma unroll
            for (int i = 0; i < 4; i++) {
                acc[i][j] = __builtin_amdgcn_mfma_f32_16x16x32_f16(ah[i], bh, acc[i][j], 0, 0, 0);
                acc[i][j] = __builtin_amdgcn_mfma_f32_16x16x32_f16(ah[i], bl, acc[i][j], 0, 0, 0);
                acc[i][j] = __builtin_amdgcn_mfma_f32_16x16x32_f16(al[i], bh, acc[i][j], 0, 0, 0);
            }
        }
    }

    __syncthreads();
    float* bpl = (float*)lds;
    for (int n = tid; n < NSTEPS * 128; n += 256)
        bpl[n] = bp[(n >> 7) * NH + h0 + (n & 127)];
    __syncthreads();

    float part[16];
#pragma unroll
    for (int e = 0; e < 16; e++) part[e] = 0.f;
#pragma unroll
    for (int j = 0; j < 4; j++) {
        const int hl = whh + 16 * j + col;
        const int h = h0 + hl;
        const float w2 = W2[h];
        const float bj = b1[h];
        float x1[16];
        int cnt[16];
#pragma unroll
        for (int e = 0; e < 16; e++) {
            x1[e] = acc[e >> 2][j][e & 3] + bj;
            cnt[e] = 0;
        }
#pragma unroll
        for (int k = 0; k < NSTEPS; k++) {
            const float c = bpl[k * 128 + hl];
#pragma unroll
            for (int e = 0; e < 16; e++) cnt[e] += (x1[e] >= c) ? 1 : 0;
        }
#pragma unroll
        for (int e = 0; e < 16; e++)
            part[e] = fmaf((float)cnt[e], w2, part[e]);
    }

    __syncthreads();
    float* red = (float*)lds;
#pragma unroll
    for (int e = 0; e < 16; e++) {
        const int row = wbb + 16 * (e >> 2) + 4 * quad + (e & 3);
        red[row * 33 + (w & 1) * 16 + col] = part[e];
    }
    __syncthreads();
    if (tid < BT) {
        float s = 0.f;
#pragma unroll
        for (int c = 0; c < 32; c++) s += red[tid * 33 + c];
        atomicAdd(&out[b0 + tid], s);
    }
}

extern "C" void kernel_launch(void* const* d_in, const int* in_sizes, int n_in,
                              void* d_out, int out_size, void* d_ws, size_t ws_size,
                              hipStream_t stream) {
    const float* x    = (const float*)d_in[0];
    const float* W1   = (const float*)d_in[1];
    const float* b1   = (const float*)d_in[2];
    const float* W2   = (const float*)d_in[3];
    const float* b2   = (const float*)d_in[4];
    const float* beta = (const float*)d_in[5];
    const float* thr  = (const float*)d_in[6];
    float* out = (float*)d_out;

    const int B = in_sizes[0] / NI;  // 32768

    // ws layout: bp (NH*32 floats) | wsplit (hi|lo interleaved) | xsplit
    char* ws = (char*)d_ws;
    float*     bp  = (float*)ws;
    size_t off = (size_t)NH * 32 * 4;                // 131072
    _Float16* wsp = (_Float16*)(ws + off);  off += (size_t)NH * NI * 4;
    _Float16* xsp = (_Float16*)(ws + off);  off += (size_t)B * NI * 4;
    const size_t ws_need = off;

    if (ws_size >= ws_need) {
        const int nblk = B / 8 + 128 + 100 + (B + 255) / 256;
        snn_prep<<<nblk, 256, 0, stream>>>(x, W1, thr, beta, b1, b2, out,
                                           bp, wsp, xsp, B);
        dim3 grid(B / BT, NH / BT);
        snn_main_fast<<<grid, 256, 0, stream>>>(xsp, wsp, W2, bp, out);
    } else {
        snn_prep_small<<<100 + (B + 255) / 256, 256, 0, stream>>>(thr, beta, b2, out, bp, B);
        dim3 grid(B / BT, NH / BT);
        snn_main_fb<<<grid, 256, 0, stream>>>(x, W1, b1, W2, bp, out);
    }
}

// Round 13
// 166.940 us; speedup vs baseline: 1.0376x; 1.0376x over previous
//
#include <hip/hip_runtime.h>

// LeakySNN fused: out[b] = b2 + sum_h spksum(x1[b,h]) * W2[h]
// R13 = R11 occupancy regime + R12 interleaved layout:
//   __launch_bounds__(256,3) RESTORED — R12's (256,4) forced scratch spill
//   (WRITE_SIZE 1->23 MB, SGPR 32->64, main 63->82us): 64 VGPR + 64 AGPR
//   = 128 leaves no headroom for fragment temporaries at 4 blocks/CU.
//   hi|lo granule interleave KEPT (one base pointer per operand, 32 B/lane
//   contiguous pair loads). Epilogue: R11 LDS binary search, stride-33 bpl.
//   b1 folded into breakpoints (exact). Fallback unchanged.

#define NI 256
#define NH 1024
#define NSTEPS 25
#define BT 128
#define BK 32
#define NTILES (NI / BK)
#define BPS 33        // bpl row stride (floats); 33 % 32 == 1 -> bank = hl+k
#define RW 40         // fallback (R6) LDS row width in halfs

typedef _Float16 half8 __attribute__((ext_vector_type(8)));
typedef _Float16 half4 __attribute__((ext_vector_type(4)));
typedef float float4v __attribute__((ext_vector_type(4)));

__device__ __forceinline__ unsigned f2k(float f) {
    unsigned u = __float_as_uint(f);
    return (u >> 31) ? ~u : (u | 0x80000000u);
}
__device__ __forceinline__ float k2f(unsigned k) {
    unsigned u = (k & 0x80000000u) ? (k & 0x7FFFFFFFu) : ~k;
    return __uint_as_float(u);
}

// 25-step LIF count, exact reference-matching arithmetic (R4/R6).
__device__ __forceinline__ int lif_count(float x1, float beta, float th) {
    float mem = 0.f;
    float spk = (0.f > th) ? 1.f : 0.f;
    int c = 0;
#pragma unroll
    for (int t = 0; t < NSTEPS; t++) {
        mem = fmaf(spk, -th, fmaf(beta, mem, x1));
        spk = (mem > th) ? 1.f : 0.f;
        c += (mem > th);
    }
    return c;
}

__device__ __forceinline__ void split8(const float* src, half8* hi, half8* lo) {
    float4v a = *(const float4v*)src;
    float4v b = *(const float4v*)(src + 4);
#pragma unroll
    for (int e = 0; e < 4; e++) {
        _Float16 h = (_Float16)a[e];
        (*hi)[e] = h;
        (*lo)[e] = (_Float16)(a[e] - (float)h);
        h = (_Float16)b[e];
        (*hi)[e + 4] = h;
        (*lo)[e + 4] = (_Float16)(b[e] - (float)h);
    }
}

// ===================== fast path =====================

// Granule-pair layout (16 halfs = hi8|lo8 of one MFMA k-chunk of one row):
//   G = band*4096 + kt*512 + r8*64 + quad*16 + col   (pair index = 2G, 2G+1)
//   holds src[row = band*128 + r8*16 + col][k = kt*32 + quad*8 .. +8]
__global__ __launch_bounds__(256) void snn_prep(
    const float* __restrict__ x, const float* __restrict__ W1,
    const float* __restrict__ thr, const float* __restrict__ betap,
    const float* __restrict__ b1, const float* __restrict__ b2,
    float* __restrict__ out, float* __restrict__ bp,
    _Float16* __restrict__ wsp, _Float16* __restrict__ xsp, int B)
{
    const int tid = threadIdx.x;
    const int XB = B / 8;            // x granules / 256
    int bid = blockIdx.x;

    if (bid < XB) {                  // ---- x split ----
        const int G = bid * 256 + tid;
        const int band = G >> 12;
        const int rem = G & 4095;
        const int kt = rem >> 9;
        const int rem2 = rem & 511;
        const int r8 = rem2 >> 6, quad = (rem2 >> 4) & 3, col = rem2 & 15;
        const float* src = x + (size_t)(band * 128 + r8 * 16 + col) * NI + kt * 32 + quad * 8;
        half8 hi, lo;
        split8(src, &hi, &lo);
        ((half8*)xsp)[2 * (size_t)G]     = hi;
        ((half8*)xsp)[2 * (size_t)G + 1] = lo;
        return;
    }
    bid -= XB;
    if (bid < 128) {                 // ---- W1 split ----
        const int G = bid * 256 + tid;   // < 32768
        const int band = G >> 12;
        const int rem = G & 4095;
        const int kt = rem >> 9;
        const int rem2 = rem & 511;
        const int r8 = rem2 >> 6, quad = (rem2 >> 4) & 3, col = rem2 & 15;
        const float* src = W1 + (size_t)(band * 128 + r8 * 16 + col) * NI + kt * 32 + quad * 8;
        half8 hi, lo;
        split8(src, &hi, &lo);
        ((half8*)wsp)[2 * (size_t)G]     = hi;
        ((half8*)wsp)[2 * (size_t)G + 1] = lo;
        return;
    }
    bid -= 128;
    if (bid < 100) {                 // ---- breakpoints, b1 folded in ----
        const int idx = bid * 256 + tid;     // exactly 25600
        const int h = idx / NSTEPS;
        const int k = idx % NSTEPS + 1;      // target count 1..25
        const float th = thr[h];
        const float bj = b1[h];
        float beta = betap[0];
        beta = beta < 0.f ? 0.f : (beta > 1.f ? 1.f : beta);
        // c'_k = smallest float a with lif_count(fl(a + bj)) >= k.
        // Then (acc >= c'_k) <=> count(fl(acc+bj)) >= k: exact (monotone).
        unsigned lo = f2k(-3.0e38f), hi = f2k(3.0e38f);
        float res;
        if (lif_count(k2f(hi) + bj, beta, th) < k) {
            res = 3.0e38f;
        } else if (lif_count(k2f(lo) + bj, beta, th) >= k) {
            res = -3.0e38f;
        } else {
#pragma unroll 1
            for (int it = 0; it < 32; it++) {
                unsigned mid = lo + ((hi - lo) >> 1);
                if (lif_count(k2f(mid) + bj, beta, th) >= k) hi = mid; else lo = mid;
            }
            res = k2f(hi);
        }
        bp[h * 32 + (k - 1)] = res;   // [h][32] layout, coalesced staging
        return;
    }
    bid -= 100;
    {                                // ---- out init ----
        const int i = bid * 256 + tid;
        if (i < B) out[i] = b2[0];
    }
}

__global__ __launch_bounds__(256, 3) void snn_main_fast(
    const _Float16* __restrict__ xsp, const _Float16* __restrict__ wsp,
    const float* __restrict__ W2, const float* __restrict__ bp,
    float* __restrict__ out)
{
    __shared__ float smem[128 * BPS];  // 16.9 KB: bpl[hl][33], later red[128][33]

    const int tid  = threadIdx.x;
    const int w    = tid >> 6;
    const int lane = tid & 63;
    const int col  = lane & 15;
    const int quad = lane >> 4;
    const int wbb  = (w >> 1) * 64;
    const int whh  = (w & 1) * 64;
    const int bband = blockIdx.x;
    const int hband = blockIdx.y;
    const int b0 = bband * BT;
    const int h0 = hband * BT;
    const int loff = quad * 16 + col;

    const half8* xs = (const half8*)xsp + (size_t)bband * 8192 + 2 * ((w >> 1) * 256 + loff);
    const half8* ws = (const half8*)wsp + (size_t)hband * 8192 + 2 * ((w & 1) * 256 + loff);

    // stage breakpoints early (overlaps GEMM; barrier only before use).
    // bpl[hl*33 + k] = c_{k+1} for k<25, +inf pad for 25..31.
    float* bpl = smem;
#pragma unroll
    for (int rep = 0; rep < 16; rep++) {
        const int n = tid + 256 * rep;       // 4096 = 128 rows x 32 k
        const int hl = n >> 5, k = n & 31;
        const float v = bp[(h0 + hl) * 32 + k];
        bpl[hl * BPS + k] = (k < NSTEPS) ? v : 3.0e38f;
    }

    float4v acc[4][4];
#pragma unroll
    for (int i = 0; i < 4; i++)
#pragma unroll
        for (int j = 0; j < 4; j++) acc[i][j] = (float4v){0.f, 0.f, 0.f, 0.f};

    // ---- GEMM: fragment-direct interleaved loads, compiler-scheduled ----
#pragma unroll 2
    for (int kt = 0; kt < NTILES; kt++) {
        const int gi = kt * 1024;          // half8 pairs per k-tile
        half8 ah[4], al[4], bh[4], bl[4];
#pragma unroll
        for (int i = 0; i < 4; i++) {
            ah[i] = xs[gi + i * 128];
            al[i] = xs[gi + i * 128 + 1];
        }
#pragma unroll
        for (int j = 0; j < 4; j++) {
            bh[j] = ws[gi + j * 128];
            bl[j] = ws[gi + j * 128 + 1];
        }
#pragma unroll
        for (int j = 0; j < 4; j++)
#pragma unroll
            for (int i = 0; i < 4; i++) {
                acc[i][j] = __builtin_amdgcn_mfma_f32_16x16x32_f16(ah[i], bh[j], acc[i][j], 0, 0, 0);
                acc[i][j] = __builtin_amdgcn_mfma_f32_16x16x32_f16(ah[i], bl[j], acc[i][j], 0, 0, 0);
                acc[i][j] = __builtin_amdgcn_mfma_f32_16x16x32_f16(al[i], bh[j], acc[i][j], 0, 0, 0);
            }
    }

    __syncthreads();   // bpl staged; all waves past GEMM loads

    // ---- count via 5-level branch-free binary search on the LDS pipe ----
    // m = max{k : x1 >= c_k}; c_k sorted nondecreasing, padded to 31 w/ +inf.
    float part[16];
#pragma unroll
    for (int e = 0; e < 16; e++) part[e] = 0.f;

#pragma unroll
    for (int j = 0; j < 4; j++) {
        const int hl = whh + 16 * j + col;
        const float w2 = W2[h0 + hl];
        const float* pj = bpl + hl * BPS;
        float x1[16];
        int mo[16];
#pragma unroll
        for (int e = 0; e < 16; e++) {
            x1[e] = acc[e >> 2][j][e & 3];
            mo[e] = 0;
        }
#pragma unroll
        for (int bstep = 16; bstep >= 1; bstep >>= 1) {
#pragma unroll
            for (int e = 0; e < 16; e++) {
                const float c = pj[mo[e] + bstep - 1];   // row m+bstep-1 = c_{m+bstep}
                mo[e] += (x1[e] >= c) ? bstep : 0;
            }
        }
#pragma unroll
        for (int e = 0; e < 16; e++)
            part[e] = fmaf((float)mo[e], w2, part[e]);
    }

    // ---- block reduction, one atomic per b-row ----
    __syncthreads();                   // bpl dead
    float* red = smem;                 // 128 x 33
#pragma unroll
    for (int e = 0; e < 16; e++) {
        const int row = wbb + 16 * (e >> 2) + 4 * quad + (e & 3);
        red[row * 33 + (w & 1) * 16 + col] = part[e];
    }
    __syncthreads();
    if (tid < BT) {
        float s = 0.f;
#pragma unroll
        for (int c2 = 0; c2 < 32; c2++) s += red[tid * 33 + c2];
        atomicAdd(&out[b0 + tid], s);
    }
}

// ===================== fallback path (R6-style, ws too small) =====================

__global__ __launch_bounds__(256) void snn_prep_small(
    const float* __restrict__ thr, const float* __restrict__ betap,
    const float* __restrict__ b2, float* __restrict__ out,
    float* __restrict__ bp, int B)
{
    const int tid = threadIdx.x;
    int bid = blockIdx.x;
    if (bid < 100) {
        const int idx = bid * 256 + tid;
        const int h = idx / NSTEPS;
        const int k = idx % NSTEPS + 1;
        const float th = thr[h];
        float beta = betap[0];
        beta = beta < 0.f ? 0.f : (beta > 1.f ? 1.f : beta);
        unsigned lo = f2k(-3.0e38f), hi = f2k(3.0e38f);
        float res;
        if (lif_count(k2f(hi), beta, th) < k) res = 3.0e38f;
        else if (lif_count(k2f(lo), beta, th) >= k) res = -3.0e38f;
        else {
#pragma unroll 1
            for (int it = 0; it < 32; it++) {
                unsigned mid = lo + ((hi - lo) >> 1);
                if (lif_count(k2f(mid), beta, th) >= k) hi = mid; else lo = mid;
            }
            res = k2f(hi);
        }
        bp[(k - 1) * NH + h] = res;
        return;
    }
    bid -= 100;
    const int i = bid * 256 + tid;
    if (i < B) out[i] = b2[0];
}

__global__ __launch_bounds__(256, 3) void snn_main_fb(
    const float* __restrict__ x, const float* __restrict__ W1,
    const float* __restrict__ b1, const float* __restrict__ W2,
    const float* __restrict__ bp, float* __restrict__ out)
{
    __shared__ __align__(16) _Float16 lds[4 * BT * RW];
    _Float16* xh = lds;
    _Float16* xl = lds + BT * RW;
    _Float16* wh = lds + 2 * BT * RW;
    _Float16* wl = lds + 3 * BT * RW;

    const int tid  = threadIdx.x;
    const int w    = tid >> 6;
    const int lane = tid & 63;
    const int col  = lane & 15;
    const int quad = lane >> 4;
    const int wbb  = (w >> 1) * 64;
    const int whh  = (w & 1) * 64;
    const int b0 = blockIdx.x * BT;
    const int h0 = blockIdx.y * BT;

    float4v acc[4][4];
#pragma unroll
    for (int i = 0; i < 4; i++)
#pragma unroll
        for (int j = 0; j < 4; j++) acc[i][j] = (float4v){0.f, 0.f, 0.f, 0.f};

    const int r0 = tid >> 3;
    const int c4 = tid & 7;
    const float* xrow = x + (size_t)(b0 + r0) * NI + 4 * c4;
    const float* wrow = W1 + (size_t)(h0 + r0) * NI + 4 * c4;

    for (int kt = 0; kt < NTILES; kt++) {
        const int ko = kt * BK;
        float4v vx[4], vw[4];
#pragma unroll
        for (int p = 0; p < 4; p++) {
            vx[p] = *(const float4v*)(xrow + (size_t)(32 * p) * NI + ko);
            vw[p] = *(const float4v*)(wrow + (size_t)(32 * p) * NI + ko);
        }
        __syncthreads();
#pragma unroll
        for (int p = 0; p < 4; p++) {
            const int row = r0 + 32 * p;
            half4 hx, lx, hw, lw;
#pragma unroll
            for (int q = 0; q < 4; q++) {
                float v = vx[p][q];
                _Float16 h = (_Float16)v;
                hx[q] = h;
                lx[q] = (_Float16)(v - (float)h);
                v = vw[p][q];
                h = (_Float16)v;
                hw[q] = h;
                lw[q] = (_Float16)(v - (float)h);
            }
            *(half4*)&xh[row * RW + 4 * c4] = hx;
            *(half4*)&xl[row * RW + 4 * c4] = lx;
            *(half4*)&wh[row * RW + 4 * c4] = hw;
            *(half4*)&wl[row * RW + 4 * c4] = lw;
        }
        __syncthreads();

        half8 ah[4], al[4];
#pragma unroll
        for (int i = 0; i < 4; i++) {
            ah[i] = *(const half8*)&xh[(wbb + 16 * i + col) * RW + 8 * quad];
            al[i] = *(const half8*)&xl[(wbb + 16 * i + col) * RW + 8 * quad];
        }
#pragma unroll
        for (int j = 0; j < 4; j++) {
            half8 bh = *(const half8*)&wh[(whh + 16 * j + col) * RW + 8 * quad];
            half8 bl = *(const half8*)&wl[(whh + 16 * j + col) * RW + 8 * quad];
#pragma unroll
            for (int i = 0; i < 4; i++) {
                acc[i][j] = __builtin_amdgcn_mfma_f32_16x16x32_f16(ah[i], bh, acc[i][j], 0, 0, 0);
                acc[i][j] = __builtin_amdgcn_mfma_f32_16x16x32_f16(ah[i], bl, acc[i][j], 0, 0, 0);
                acc[i][j] = __builtin_amdgcn_mfma_f32_16x16x32_f16(al[i], bh, acc[i][j], 0, 0, 0);
            }
        }
    }

    __syncthreads();
    float* bpl = (float*)lds;
    for (int n = tid; n < NSTEPS * 128; n += 256)
        bpl[n] = bp[(n >> 7) * NH + h0 + (n & 127)];
    __syncthreads();

    float part[16];
#pragma unroll
    for (int e = 0; e < 16; e++) part[e] = 0.f;
#pragma unroll
    for (int j = 0; j < 4; j++) {
        const int hl = whh + 16 * j + col;
        const int h = h0 + hl;
        const float w2 = W2[h];
        const float bj = b1[h];
        float x1[16];
        int cnt[16];
#pragma unroll
        for (int e = 0; e < 16; e++) {
            x1[e] = acc[e >> 2][j][e & 3] + bj;
            cnt[e] = 0;
        }
#pragma unroll
        for (int k = 0; k < NSTEPS; k++) {
            const float c = bpl[k * 128 + hl];
#pragma unroll
            for (int e = 0; e < 16; e++) cnt[e] += (x1[e] >= c) ? 1 : 0;
        }
#pragma unroll
        for (int e = 0; e < 16; e++)
            part[e] = fmaf((float)cnt[e], w2, part[e]);
    }

    __syncthreads();
    float* red = (float*)lds;
#pragma unroll
    for (int e = 0; e < 16; e++) {
        const int row = wbb + 16 * (e >> 2) + 4 * quad + (e & 3);
        red[row * 33 + (w & 1) * 16 + col] = part[e];
    }
    __syncthreads();
    if (tid < BT) {
        float s = 0.f;
#pragma unroll
        for (int c = 0; c < 32; c++) s += red[tid * 33 + c];
        atomicAdd(&out[b0 + tid], s);
    }
}

extern "C" void kernel_launch(void* const* d_in, const int* in_sizes, int n_in,
                              void* d_out, int out_size, void* d_ws, size_t ws_size,
                              hipStream_t stream) {
    const float* x    = (const float*)d_in[0];
    const float* W1   = (const float*)d_in[1];
    const float* b1   = (const float*)d_in[2];
    const float* W2   = (const float*)d_in[3];
    const float* b2   = (const float*)d_in[4];
    const float* beta = (const float*)d_in[5];
    const float* thr  = (const float*)d_in[6];
    float* out = (float*)d_out;

    const int B = in_sizes[0] / NI;  // 32768

    // ws layout: bp (NH*32 floats) | wsplit (hi|lo interleaved) | xsplit
    char* ws = (char*)d_ws;
    float*     bp  = (float*)ws;
    size_t off = (size_t)NH * 32 * 4;                // 131072
    _Float16* wsp = (_Float16*)(ws + off);  off += (size_t)NH * NI * 4;
    _Float16* xsp = (_Float16*)(ws + off);  off += (size_t)B * NI * 4;
    const size_t ws_need = off;

    if (ws_size >= ws_need) {
        const int nblk = B / 8 + 128 + 100 + (B + 255) / 256;
        snn_prep<<<nblk, 256, 0, stream>>>(x, W1, thr, beta, b1, b2, out,
                                           bp, wsp, xsp, B);
        dim3 grid(B / BT, NH / BT);
        snn_main_fast<<<grid, 256, 0, stream>>>(xsp, wsp, W2, bp, out);
    } else {
        snn_prep_small<<<100 + (B + 255) / 256, 256, 0, stream>>>(thr, beta, b2, out, bp, B);
        dim3 grid(B / BT, NH / BT);
        snn_main_fb<<<grid, 256, 0, stream>>>(x, W1, b1, W2, bp, out);
    }
}

// Round 14
// 147.651 us; speedup vs baseline: 1.1731x; 1.1306x over previous
//
#include <hip/hip_runtime.h>

// LeakySNN fused: out[b] = b2 + sum_h spksum(x1[b,h]) * W2[h]
// R14 = R11 structure (separate flat fragment arrays, launch_bounds(256,3),
//   LDS binary-search epilogue, stride-33 bpl, b1 folded into breakpoints)
//   with the GEMM cut from 3 terms to 2: x1 ~= fl16(x)·(wh + wl), W split
//   exactly, xl·w term DROPPED (error std ~1.2e-4 on x1 ~ N(0,1); flip
//   analysis gives absmax ~0.3 vs 0.72 threshold). Per k-tile: 12 fragment
//   loads (was 16), 32 MFMA (was 48); xh array halves x-side L2 traffic and
//   prep writes. R12's (256,4) bound and R13's interleave stay reverted
//   (spill / addressing regressions).

#define NI 256
#define NH 1024
#define NSTEPS 25
#define BT 128
#define BK 32
#define NTILES (NI / BK)
#define BPS 33        // bpl row stride (floats); 33 % 32 == 1 -> bank = hl+k
#define RW 40         // fallback (R6) LDS row width in halfs

typedef _Float16 half8 __attribute__((ext_vector_type(8)));
typedef _Float16 half4 __attribute__((ext_vector_type(4)));
typedef float float4v __attribute__((ext_vector_type(4)));

__device__ __forceinline__ unsigned f2k(float f) {
    unsigned u = __float_as_uint(f);
    return (u >> 31) ? ~u : (u | 0x80000000u);
}
__device__ __forceinline__ float k2f(unsigned k) {
    unsigned u = (k & 0x80000000u) ? (k & 0x7FFFFFFFu) : ~k;
    return __uint_as_float(u);
}

// 25-step LIF count, exact reference-matching arithmetic (R4/R6).
__device__ __forceinline__ int lif_count(float x1, float beta, float th) {
    float mem = 0.f;
    float spk = (0.f > th) ? 1.f : 0.f;
    int c = 0;
#pragma unroll
    for (int t = 0; t < NSTEPS; t++) {
        mem = fmaf(spk, -th, fmaf(beta, mem, x1));
        spk = (mem > th) ? 1.f : 0.f;
        c += (mem > th);
    }
    return c;
}

__device__ __forceinline__ void split8(const float* src, half8* hi, half8* lo) {
    float4v a = *(const float4v*)src;
    float4v b = *(const float4v*)(src + 4);
#pragma unroll
    for (int e = 0; e < 4; e++) {
        _Float16 h = (_Float16)a[e];
        (*hi)[e] = h;
        (*lo)[e] = (_Float16)(a[e] - (float)h);
        h = (_Float16)b[e];
        (*hi)[e + 4] = h;
        (*lo)[e + 4] = (_Float16)(b[e] - (float)h);
    }
}

__device__ __forceinline__ void round8(const float* src, half8* hi) {
    float4v a = *(const float4v*)src;
    float4v b = *(const float4v*)(src + 4);
#pragma unroll
    for (int e = 0; e < 4; e++) {
        (*hi)[e]     = (_Float16)a[e];
        (*hi)[e + 4] = (_Float16)b[e];
    }
}

// ===================== fast path =====================

// Granule layout (8 halfs = one MFMA k-chunk of one row):
//   G = band*4096 + kt*512 + r8*64 + quad*16 + col
//   holds src[row = band*128 + r8*16 + col][k = kt*32 + quad*8 .. +8]
__global__ __launch_bounds__(256) void snn_prep(
    const float* __restrict__ x, const float* __restrict__ W1,
    const float* __restrict__ thr, const float* __restrict__ betap,
    const float* __restrict__ b1, const float* __restrict__ b2,
    float* __restrict__ out, float* __restrict__ bp,
    _Float16* __restrict__ whp, _Float16* __restrict__ wlp,
    _Float16* __restrict__ xhp, int B)
{
    const int tid = threadIdx.x;
    const int XB = B / 8;            // x granules / 256
    int bid = blockIdx.x;

    if (bid < XB) {                  // ---- x round to fp16 (hi only) ----
        const int G = bid * 256 + tid;
        const int band = G >> 12;
        const int rem = G & 4095;
        const int kt = rem >> 9;
        const int rem2 = rem & 511;
        const int r8 = rem2 >> 6, quad = (rem2 >> 4) & 3, col = rem2 & 15;
        const float* src = x + (size_t)(band * 128 + r8 * 16 + col) * NI + kt * 32 + quad * 8;
        half8 hi;
        round8(src, &hi);
        ((half8*)xhp)[G] = hi;
        return;
    }
    bid -= XB;
    if (bid < 128) {                 // ---- W1 exact two-term split ----
        const int G = bid * 256 + tid;   // < 32768
        const int band = G >> 12;
        const int rem = G & 4095;
        const int kt = rem >> 9;
        const int rem2 = rem & 511;
        const int r8 = rem2 >> 6, quad = (rem2 >> 4) & 3, col = rem2 & 15;
        const float* src = W1 + (size_t)(band * 128 + r8 * 16 + col) * NI + kt * 32 + quad * 8;
        half8 hi, lo;
        split8(src, &hi, &lo);
        ((half8*)whp)[G] = hi;
        ((half8*)wlp)[G] = lo;
        return;
    }
    bid -= 128;
    if (bid < 100) {                 // ---- breakpoints, b1 folded in ----
        const int idx = bid * 256 + tid;     // exactly 25600
        const int h = idx / NSTEPS;
        const int k = idx % NSTEPS + 1;      // target count 1..25
        const float th = thr[h];
        const float bj = b1[h];
        float beta = betap[0];
        beta = beta < 0.f ? 0.f : (beta > 1.f ? 1.f : beta);
        // c'_k = smallest float a with lif_count(fl(a + bj)) >= k.
        // Then (acc >= c'_k) <=> count(fl(acc+bj)) >= k: exact (monotone).
        unsigned lo = f2k(-3.0e38f), hi = f2k(3.0e38f);
        float res;
        if (lif_count(k2f(hi) + bj, beta, th) < k) {
            res = 3.0e38f;
        } else if (lif_count(k2f(lo) + bj, beta, th) >= k) {
            res = -3.0e38f;
        } else {
#pragma unroll 1
            for (int it = 0; it < 32; it++) {
                unsigned mid = lo + ((hi - lo) >> 1);
                if (lif_count(k2f(mid) + bj, beta, th) >= k) hi = mid; else lo = mid;
            }
            res = k2f(hi);
        }
        bp[h * 32 + (k - 1)] = res;   // [h][32] layout, coalesced staging
        return;
    }
    bid -= 100;
    {                                // ---- out init ----
        const int i = bid * 256 + tid;
        if (i < B) out[i] = b2[0];
    }
}

__global__ __launch_bounds__(256, 3) void snn_main_fast(
    const _Float16* __restrict__ xhp, const _Float16* __restrict__ whp,
    const _Float16* __restrict__ wlp, const float* __restrict__ W2,
    const float* __restrict__ bp, float* __restrict__ out)
{
    __shared__ float smem[128 * BPS];  // 16.9 KB: bpl[hl][33], later red[128][33]

    const int tid  = threadIdx.x;
    const int w    = tid >> 6;
    const int lane = tid & 63;
    const int col  = lane & 15;
    const int quad = lane >> 4;
    const int wbb  = (w >> 1) * 64;
    const int whh  = (w & 1) * 64;
    const int bband = blockIdx.x;
    const int hband = blockIdx.y;
    const int b0 = bband * BT;
    const int h0 = hband * BT;
    const int loff = quad * 16 + col;

    const half8* xh = (const half8*)xhp + (size_t)bband * 4096 + (w >> 1) * 256 + loff;
    const half8* wh = (const half8*)whp + (size_t)hband * 4096 + (w & 1) * 256 + loff;
    const half8* wl = (const half8*)wlp + (size_t)hband * 4096 + (w & 1) * 256 + loff;

    // stage breakpoints early (overlaps GEMM; barrier only before use).
    // bpl[hl*33 + k] = c_{k+1} for k<25, +inf pad for 25..31.
    float* bpl = smem;
#pragma unroll
    for (int rep = 0; rep < 16; rep++) {
        const int n = tid + 256 * rep;       // 4096 = 128 rows x 32 k
        const int hl = n >> 5, k = n & 31;
        const float v = bp[(h0 + hl) * 32 + k];
        bpl[hl * BPS + k] = (k < NSTEPS) ? v : 3.0e38f;
    }

    float4v acc[4][4];
#pragma unroll
    for (int i = 0; i < 4; i++)
#pragma unroll
        for (int j = 0; j < 4; j++) acc[i][j] = (float4v){0.f, 0.f, 0.f, 0.f};

    // ---- GEMM: 2-term fragment-direct, compiler-scheduled ----
#pragma unroll 2
    for (int kt = 0; kt < NTILES; kt++) {
        const int gi = kt * 512;
        half8 ah[4], bh[4], bl[4];
#pragma unroll
        for (int i = 0; i < 4; i++) ah[i] = xh[gi + i * 64];
#pragma unroll
        for (int j = 0; j < 4; j++) {
            bh[j] = wh[gi + j * 64];
            bl[j] = wl[gi + j * 64];
        }
#pragma unroll
        for (int j = 0; j < 4; j++)
#pragma unroll
            for (int i = 0; i < 4; i++) {
                acc[i][j] = __builtin_amdgcn_mfma_f32_16x16x32_f16(ah[i], bh[j], acc[i][j], 0, 0, 0);
                acc[i][j] = __builtin_amdgcn_mfma_f32_16x16x32_f16(ah[i], bl[j], acc[i][j], 0, 0, 0);
            }
    }

    __syncthreads();   // bpl staged; all waves past GEMM loads

    // ---- count via 5-level branch-free binary search on the LDS pipe ----
    // m = max{k : x1 >= c_k}; c_k sorted nondecreasing, padded to 31 w/ +inf.
    float part[16];
#pragma unroll
    for (int e = 0; e < 16; e++) part[e] = 0.f;

#pragma unroll
    for (int j = 0; j < 4; j++) {
        const int hl = whh + 16 * j + col;
        const float w2 = W2[h0 + hl];
        const float* pj = bpl + hl * BPS;
        float x1[16];
        int mo[16];
#pragma unroll
        for (int e = 0; e < 16; e++) {
            x1[e] = acc[e >> 2][j][e & 3];
            mo[e] = 0;
        }
#pragma unroll
        for (int bstep = 16; bstep >= 1; bstep >>= 1) {
#pragma unroll
            for (int e = 0; e < 16; e++) {
                const float c = pj[mo[e] + bstep - 1];   // row m+bstep-1 = c_{m+bstep}
                mo[e] += (x1[e] >= c) ? bstep : 0;
            }
        }
#pragma unroll
        for (int e = 0; e < 16; e++)
            part[e] = fmaf((float)mo[e], w2, part[e]);
    }

    // ---- block reduction, one atomic per b-row ----
    __syncthreads();                   // bpl dead
    float* red = smem;                 // 128 x 33
#pragma unroll
    for (int e = 0; e < 16; e++) {
        const int row = wbb + 16 * (e >> 2) + 4 * quad + (e & 3);
        red[row * 33 + (w & 1) * 16 + col] = part[e];
    }
    __syncthreads();
    if (tid < BT) {
        float s = 0.f;
#pragma unroll
        for (int c2 = 0; c2 < 32; c2++) s += red[tid * 33 + c2];
        atomicAdd(&out[b0 + tid], s);
    }
}

// ===================== fallback path (R6-style, ws too small) =====================

__global__ __launch_bounds__(256) void snn_prep_small(
    const float* __restrict__ thr, const float* __restrict__ betap,
    const float* __restrict__ b2, float* __restrict__ out,
    float* __restrict__ bp, int B)
{
    const int tid = threadIdx.x;
    int bid = blockIdx.x;
    if (bid < 100) {
        const int idx = bid * 256 + tid;
        const int h = idx / NSTEPS;
        const int k = idx % NSTEPS + 1;
        const float th = thr[h];
        float beta = betap[0];
        beta = beta < 0.f ? 0.f : (beta > 1.f ? 1.f : beta);
        unsigned lo = f2k(-3.0e38f), hi = f2k(3.0e38f);
        float res;
        if (lif_count(k2f(hi), beta, th) < k) res = 3.0e38f;
        else if (lif_count(k2f(lo), beta, th) >= k) res = -3.0e38f;
        else {
#pragma unroll 1
            for (int it = 0; it < 32; it++) {
                unsigned mid = lo + ((hi - lo) >> 1);
                if (lif_count(k2f(mid), beta, th) >= k) hi = mid; else lo = mid;
            }
            res = k2f(hi);
        }
        bp[(k - 1) * NH + h] = res;
        return;
    }
    bid -= 100;
    const int i = bid * 256 + tid;
    if (i < B) out[i] = b2[0];
}

__global__ __launch_bounds__(256, 3) void snn_main_fb(
    const float* __restrict__ x, const float* __restrict__ W1,
    const float* __restrict__ b1, const float* __restrict__ W2,
    const float* __restrict__ bp, float* __restrict__ out)
{
    __shared__ __align__(16) _Float16 lds[4 * BT * RW];
    _Float16* xh = lds;
    _Float16* xl = lds + BT * RW;
    _Float16* wh = lds + 2 * BT * RW;
    _Float16* wl = lds + 3 * BT * RW;

    const int tid  = threadIdx.x;
    const int w    = tid >> 6;
    const int lane = tid & 63;
    const int col  = lane & 15;
    const int quad = lane >> 4;
    const int wbb  = (w >> 1) * 64;
    const int whh  = (w & 1) * 64;
    const int b0 = blockIdx.x * BT;
    const int h0 = blockIdx.y * BT;

    float4v acc[4][4];
#pragma unroll
    for (int i = 0; i < 4; i++)
#pragma unroll
        for (int j = 0; j < 4; j++) acc[i][j] = (float4v){0.f, 0.f, 0.f, 0.f};

    const int r0 = tid >> 3;
    const int c4 = tid & 7;
    const float* xrow = x + (size_t)(b0 + r0) * NI + 4 * c4;
    const float* wrow = W1 + (size_t)(h0 + r0) * NI + 4 * c4;

    for (int kt = 0; kt < NTILES; kt++) {
        const int ko = kt * BK;
        float4v vx[4], vw[4];
#pragma unroll
        for (int p = 0; p < 4; p++) {
            vx[p] = *(const float4v*)(xrow + (size_t)(32 * p) * NI + ko);
            vw[p] = *(const float4v*)(wrow + (size_t)(32 * p) * NI + ko);
        }
        __syncthreads();
#pragma unroll
        for (int p = 0; p < 4; p++) {
            const int row = r0 + 32 * p;
            half4 hx, lx, hw, lw;
#pragma unroll
            for (int q = 0; q < 4; q++) {
                float v = vx[p][q];
                _Float16 h = (_Float16)v;
                hx[q] = h;
                lx[q] = (_Float16)(v - (float)h);
                v = vw[p][q];
                h = (_Float16)v;
                hw[q] = h;
                lw[q] = (_Float16)(v - (float)h);
            }
            *(half4*)&xh[row * RW + 4 * c4] = hx;
            *(half4*)&xl[row * RW + 4 * c4] = lx;
            *(half4*)&wh[row * RW + 4 * c4] = hw;
            *(half4*)&wl[row * RW + 4 * c4] = lw;
        }
        __syncthreads();

        half8 ah[4], al[4];
#pragma unroll
        for (int i = 0; i < 4; i++) {
            ah[i] = *(const half8*)&xh[(wbb + 16 * i + col) * RW + 8 * quad];
            al[i] = *(const half8*)&xl[(wbb + 16 * i + col) * RW + 8 * quad];
        }
#pragma unroll
        for (int j = 0; j < 4; j++) {
            half8 bh = *(const half8*)&wh[(whh + 16 * j + col) * RW + 8 * quad];
            half8 bl = *(const half8*)&wl[(whh + 16 * j + col) * RW + 8 * quad];
#pragma unroll
            for (int i = 0; i < 4; i++) {
                acc[i][j] = __builtin_amdgcn_mfma_f32_16x16x32_f16(ah[i], bh, acc[i][j], 0, 0, 0);
                acc[i][j] = __builtin_amdgcn_mfma_f32_16x16x32_f16(ah[i], bl, acc[i][j], 0, 0, 0);
                acc[i][j] = __builtin_amdgcn_mfma_f32_16x16x32_f16(al[i], bh, acc[i][j], 0, 0, 0);
            }
        }
    }

    __syncthreads();
    float* bpl = (float*)lds;
    for (int n = tid; n < NSTEPS * 128; n += 256)
        bpl[n] = bp[(n >> 7) * NH + h0 + (n & 127)];
    __syncthreads();

    float part[16];
#pragma unroll
    for (int e = 0; e < 16; e++) part[e] = 0.f;
#pragma unroll
    for (int j = 0; j < 4; j++) {
        const int hl = whh + 16 * j + col;
        const int h = h0 + hl;
        const float w2 = W2[h];
        const float bj = b1[h];
        float x1[16];
        int cnt[16];
#pragma unroll
        for (int e = 0; e < 16; e++) {
            x1[e] = acc[e >> 2][j][e & 3] + bj;
            cnt[e] = 0;
        }
#pragma unroll
        for (int k = 0; k < NSTEPS; k++) {
            const float c = bpl[k * 128 + hl];
#pragma unroll
            for (int e = 0; e < 16; e++) cnt[e] += (x1[e] >= c) ? 1 : 0;
        }
#pragma unroll
        for (int e = 0; e < 16; e++)
            part[e] = fmaf((float)cnt[e], w2, part[e]);
    }

    __syncthreads();
    float* red = (float*)lds;
#pragma unroll
    for (int e = 0; e < 16; e++) {
        const int row = wbb + 16 * (e >> 2) + 4 * quad + (e & 3);
        red[row * 33 + (w & 1) * 16 + col] = part[e];
    }
    __syncthreads();
    if (tid < BT) {
        float s = 0.f;
#pragma unroll
        for (int c = 0; c < 32; c++) s += red[tid * 33 + c];
        atomicAdd(&out[b0 + tid], s);
    }
}

extern "C" void kernel_launch(void* const* d_in, const int* in_sizes, int n_in,
                              void* d_out, int out_size, void* d_ws, size_t ws_size,
                              hipStream_t stream) {
    const float* x    = (const float*)d_in[0];
    const float* W1   = (const float*)d_in[1];
    const float* b1   = (const float*)d_in[2];
    const float* W2   = (const float*)d_in[3];
    const float* b2   = (const float*)d_in[4];
    const float* beta = (const float*)d_in[5];
    const float* thr  = (const float*)d_in[6];
    float* out = (float*)d_out;

    const int B = in_sizes[0] / NI;  // 32768

    // ws layout: bp (NH*32 floats) | wh | wl | xh
    char* ws = (char*)d_ws;
    float*     bp  = (float*)ws;
    size_t off = (size_t)NH * 32 * 4;                // 131072
    _Float16* whp = (_Float16*)(ws + off);  off += (size_t)NH * NI * 2;
    _Float16* wlp = (_Float16*)(ws + off);  off += (size_t)NH * NI * 2;
    _Float16* xhp = (_Float16*)(ws + off);  off += (size_t)B * NI * 2;
    const size_t ws_need = off;

    if (ws_size >= ws_need) {
        const int nblk = B / 8 + 128 + 100 + (B + 255) / 256;
        snn_prep<<<nblk, 256, 0, stream>>>(x, W1, thr, beta, b1, b2, out,
                                           bp, whp, wlp, xhp, B);
        dim3 grid(B / BT, NH / BT);
        snn_main_fast<<<grid, 256, 0, stream>>>(xhp, whp, wlp, W2, bp, out);
    } else {
        snn_prep_small<<<100 + (B + 255) / 256, 256, 0, stream>>>(thr, beta, b2, out, bp, B);
        dim3 grid(B / BT, NH / BT);
        snn_main_fb<<<grid, 256, 0, stream>>>(x, W1, b1, W2, bp, out);
    }
}

// Round 15
// 146.674 us; speedup vs baseline: 1.1810x; 1.0067x over previous
//
#include <hip/hip_runtime.h>

// LeakySNN fused: out[b] = b2 + sum_h spksum(x1[b,h]) * W2[h]
// R15 = R14 (2-term fp16-split MFMA GEMM, fragment-direct, LDS binary-search
//   epilogue, b1-folded breakpoints) + occupancy push:
//   __launch_bounds__(256,4) — with the 2-term GEMM the K-loop holds only
//   12 fragment temps (~58 VGPR), and the epilogue is restructured into two
//   8-element halves (x1[8]+mo[8] = 16 regs vs 32) so peak pressure fits
//   the 128-reg/wave budget (64 VGPR + 64 AGPR) that R12's 3-term variant
//   overflowed. Spill signature to watch: WRITE_SIZE >> 1 MB -> revert.

#define NI 256
#define NH 1024
#define NSTEPS 25
#define BT 128
#define BK 32
#define NTILES (NI / BK)
#define BPS 33        // bpl row stride (floats); 33 % 32 == 1 -> bank = hl+k
#define RW 40         // fallback (R6) LDS row width in halfs

typedef _Float16 half8 __attribute__((ext_vector_type(8)));
typedef _Float16 half4 __attribute__((ext_vector_type(4)));
typedef float float4v __attribute__((ext_vector_type(4)));

__device__ __forceinline__ unsigned f2k(float f) {
    unsigned u = __float_as_uint(f);
    return (u >> 31) ? ~u : (u | 0x80000000u);
}
__device__ __forceinline__ float k2f(unsigned k) {
    unsigned u = (k & 0x80000000u) ? (k & 0x7FFFFFFFu) : ~k;
    return __uint_as_float(u);
}

// 25-step LIF count, exact reference-matching arithmetic (R4/R6).
__device__ __forceinline__ int lif_count(float x1, float beta, float th) {
    float mem = 0.f;
    float spk = (0.f > th) ? 1.f : 0.f;
    int c = 0;
#pragma unroll
    for (int t = 0; t < NSTEPS; t++) {
        mem = fmaf(spk, -th, fmaf(beta, mem, x1));
        spk = (mem > th) ? 1.f : 0.f;
        c += (mem > th);
    }
    return c;
}

__device__ __forceinline__ void split8(const float* src, half8* hi, half8* lo) {
    float4v a = *(const float4v*)src;
    float4v b = *(const float4v*)(src + 4);
#pragma unroll
    for (int e = 0; e < 4; e++) {
        _Float16 h = (_Float16)a[e];
        (*hi)[e] = h;
        (*lo)[e] = (_Float16)(a[e] - (float)h);
        h = (_Float16)b[e];
        (*hi)[e + 4] = h;
        (*lo)[e + 4] = (_Float16)(b[e] - (float)h);
    }
}

__device__ __forceinline__ void round8(const float* src, half8* hi) {
    float4v a = *(const float4v*)src;
    float4v b = *(const float4v*)(src + 4);
#pragma unroll
    for (int e = 0; e < 4; e++) {
        (*hi)[e]     = (_Float16)a[e];
        (*hi)[e + 4] = (_Float16)b[e];
    }
}

// ===================== fast path =====================

// Granule layout (8 halfs = one MFMA k-chunk of one row):
//   G = band*4096 + kt*512 + r8*64 + quad*16 + col
//   holds src[row = band*128 + r8*16 + col][k = kt*32 + quad*8 .. +8]
__global__ __launch_bounds__(256) void snn_prep(
    const float* __restrict__ x, const float* __restrict__ W1,
    const float* __restrict__ thr, const float* __restrict__ betap,
    const float* __restrict__ b1, const float* __restrict__ b2,
    float* __restrict__ out, float* __restrict__ bp,
    _Float16* __restrict__ whp, _Float16* __restrict__ wlp,
    _Float16* __restrict__ xhp, int B)
{
    const int tid = threadIdx.x;
    const int XB = B / 8;            // x granules / 256
    int bid = blockIdx.x;

    if (bid < XB) {                  // ---- x round to fp16 (hi only) ----
        const int G = bid * 256 + tid;
        const int band = G >> 12;
        const int rem = G & 4095;
        const int kt = rem >> 9;
        const int rem2 = rem & 511;
        const int r8 = rem2 >> 6, quad = (rem2 >> 4) & 3, col = rem2 & 15;
        const float* src = x + (size_t)(band * 128 + r8 * 16 + col) * NI + kt * 32 + quad * 8;
        half8 hi;
        round8(src, &hi);
        ((half8*)xhp)[G] = hi;
        return;
    }
    bid -= XB;
    if (bid < 128) {                 // ---- W1 exact two-term split ----
        const int G = bid * 256 + tid;   // < 32768
        const int band = G >> 12;
        const int rem = G & 4095;
        const int kt = rem >> 9;
        const int rem2 = rem & 511;
        const int r8 = rem2 >> 6, quad = (rem2 >> 4) & 3, col = rem2 & 15;
        const float* src = W1 + (size_t)(band * 128 + r8 * 16 + col) * NI + kt * 32 + quad * 8;
        half8 hi, lo;
        split8(src, &hi, &lo);
        ((half8*)whp)[G] = hi;
        ((half8*)wlp)[G] = lo;
        return;
    }
    bid -= 128;
    if (bid < 100) {                 // ---- breakpoints, b1 folded in ----
        const int idx = bid * 256 + tid;     // exactly 25600
        const int h = idx / NSTEPS;
        const int k = idx % NSTEPS + 1;      // target count 1..25
        const float th = thr[h];
        const float bj = b1[h];
        float beta = betap[0];
        beta = beta < 0.f ? 0.f : (beta > 1.f ? 1.f : beta);
        // c'_k = smallest float a with lif_count(fl(a + bj)) >= k.
        // Then (acc >= c'_k) <=> count(fl(acc+bj)) >= k: exact (monotone).
        unsigned lo = f2k(-3.0e38f), hi = f2k(3.0e38f);
        float res;
        if (lif_count(k2f(hi) + bj, beta, th) < k) {
            res = 3.0e38f;
        } else if (lif_count(k2f(lo) + bj, beta, th) >= k) {
            res = -3.0e38f;
        } else {
#pragma unroll 1
            for (int it = 0; it < 32; it++) {
                unsigned mid = lo + ((hi - lo) >> 1);
                if (lif_count(k2f(mid) + bj, beta, th) >= k) hi = mid; else lo = mid;
            }
            res = k2f(hi);
        }
        bp[h * 32 + (k - 1)] = res;   // [h][32] layout, coalesced staging
        return;
    }
    bid -= 100;
    {                                // ---- out init ----
        const int i = bid * 256 + tid;
        if (i < B) out[i] = b2[0];
    }
}

__global__ __launch_bounds__(256, 4) void snn_main_fast(
    const _Float16* __restrict__ xhp, const _Float16* __restrict__ whp,
    const _Float16* __restrict__ wlp, const float* __restrict__ W2,
    const float* __restrict__ bp, float* __restrict__ out)
{
    __shared__ float smem[128 * BPS];  // 16.9 KB: bpl[hl][33], later red[128][33]

    const int tid  = threadIdx.x;
    const int w    = tid >> 6;
    const int lane = tid & 63;
    const int col  = lane & 15;
    const int quad = lane >> 4;
    const int wbb  = (w >> 1) * 64;
    const int whh  = (w & 1) * 64;
    const int bband = blockIdx.x;
    const int hband = blockIdx.y;
    const int b0 = bband * BT;
    const int h0 = hband * BT;
    const int loff = quad * 16 + col;

    const half8* xh = (const half8*)xhp + (size_t)bband * 4096 + (w >> 1) * 256 + loff;
    const half8* wh = (const half8*)whp + (size_t)hband * 4096 + (w & 1) * 256 + loff;
    const half8* wl = (const half8*)wlp + (size_t)hband * 4096 + (w & 1) * 256 + loff;

    // stage breakpoints early (overlaps GEMM; barrier only before use).
    // bpl[hl*33 + k] = c_{k+1} for k<25, +inf pad for 25..31.
    float* bpl = smem;
#pragma unroll
    for (int rep = 0; rep < 16; rep++) {
        const int n = tid + 256 * rep;       // 4096 = 128 rows x 32 k
        const int hl = n >> 5, k = n & 31;
        const float v = bp[(h0 + hl) * 32 + k];
        bpl[hl * BPS + k] = (k < NSTEPS) ? v : 3.0e38f;
    }

    float4v acc[4][4];
#pragma unroll
    for (int i = 0; i < 4; i++)
#pragma unroll
        for (int j = 0; j < 4; j++) acc[i][j] = (float4v){0.f, 0.f, 0.f, 0.f};

    // ---- GEMM: 2-term fragment-direct, compiler-scheduled ----
#pragma unroll 2
    for (int kt = 0; kt < NTILES; kt++) {
        const int gi = kt * 512;
        half8 ah[4], bh[4], bl[4];
#pragma unroll
        for (int i = 0; i < 4; i++) ah[i] = xh[gi + i * 64];
#pragma unroll
        for (int j = 0; j < 4; j++) {
            bh[j] = wh[gi + j * 64];
            bl[j] = wl[gi + j * 64];
        }
#pragma unroll
        for (int j = 0; j < 4; j++)
#pragma unroll
            for (int i = 0; i < 4; i++) {
                acc[i][j] = __builtin_amdgcn_mfma_f32_16x16x32_f16(ah[i], bh[j], acc[i][j], 0, 0, 0);
                acc[i][j] = __builtin_amdgcn_mfma_f32_16x16x32_f16(ah[i], bl[j], acc[i][j], 0, 0, 0);
            }
    }

    __syncthreads();   // bpl staged; all waves past GEMM loads

    // ---- count via 5-level branch-free binary search on the LDS pipe ----
    // m = max{k : x1 >= c_k}; c_k sorted nondecreasing, padded to 31 w/ +inf.
    // Processed in two 8-element halves to cap register pressure (4 blk/CU).
    float part[16];
#pragma unroll
    for (int e = 0; e < 16; e++) part[e] = 0.f;

#pragma unroll
    for (int j = 0; j < 4; j++) {
        const int hl = whh + 16 * j + col;
        const float w2 = W2[h0 + hl];
        const float* pj = bpl + hl * BPS;
#pragma unroll
        for (int half = 0; half < 2; half++) {
            float x1[8];
            int mo[8];
#pragma unroll
            for (int e = 0; e < 8; e++) {
                const int ee = e + 8 * half;
                x1[e] = acc[ee >> 2][j][ee & 3];
                mo[e] = 0;
            }
#pragma unroll
            for (int bstep = 16; bstep >= 1; bstep >>= 1) {
#pragma unroll
                for (int e = 0; e < 8; e++) {
                    const float c = pj[mo[e] + bstep - 1];   // row m+bstep-1 = c_{m+bstep}
                    mo[e] += (x1[e] >= c) ? bstep : 0;
                }
            }
#pragma unroll
            for (int e = 0; e < 8; e++)
                part[e + 8 * half] = fmaf((float)mo[e], w2, part[e + 8 * half]);
        }
    }

    // ---- block reduction, one atomic per b-row ----
    __syncthreads();                   // bpl dead
    float* red = smem;                 // 128 x 33
#pragma unroll
    for (int e = 0; e < 16; e++) {
        const int row = wbb + 16 * (e >> 2) + 4 * quad + (e & 3);
        red[row * 33 + (w & 1) * 16 + col] = part[e];
    }
    __syncthreads();
    if (tid < BT) {
        float s = 0.f;
#pragma unroll
        for (int c2 = 0; c2 < 32; c2++) s += red[tid * 33 + c2];
        atomicAdd(&out[b0 + tid], s);
    }
}

// ===================== fallback path (R6-style, ws too small) =====================

__global__ __launch_bounds__(256) void snn_prep_small(
    const float* __restrict__ thr, const float* __restrict__ betap,
    const float* __restrict__ b2, float* __restrict__ out,
    float* __restrict__ bp, int B)
{
    const int tid = threadIdx.x;
    int bid = blockIdx.x;
    if (bid < 100) {
        const int idx = bid * 256 + tid;
        const int h = idx / NSTEPS;
        const int k = idx % NSTEPS + 1;
        const float th = thr[h];
        float beta = betap[0];
        beta = beta < 0.f ? 0.f : (beta > 1.f ? 1.f : beta);
        unsigned lo = f2k(-3.0e38f), hi = f2k(3.0e38f);
        float res;
        if (lif_count(k2f(hi), beta, th) < k) res = 3.0e38f;
        else if (lif_count(k2f(lo), beta, th) >= k) res = -3.0e38f;
        else {
#pragma unroll 1
            for (int it = 0; it < 32; it++) {
                unsigned mid = lo + ((hi - lo) >> 1);
                if (lif_count(k2f(mid), beta, th) >= k) hi = mid; else lo = mid;
            }
            res = k2f(hi);
        }
        bp[(k - 1) * NH + h] = res;
        return;
    }
    bid -= 100;
    const int i = bid * 256 + tid;
    if (i < B) out[i] = b2[0];
}

__global__ __launch_bounds__(256, 3) void snn_main_fb(
    const float* __restrict__ x, const float* __restrict__ W1,
    const float* __restrict__ b1, const float* __restrict__ W2,
    const float* __restrict__ bp, float* __restrict__ out)
{
    __shared__ __align__(16) _Float16 lds[4 * BT * RW];
    _Float16* xh = lds;
    _Float16* xl = lds + BT * RW;
    _Float16* wh = lds + 2 * BT * RW;
    _Float16* wl = lds + 3 * BT * RW;

    const int tid  = threadIdx.x;
    const int w    = tid >> 6;
    const int lane = tid & 63;
    const int col  = lane & 15;
    const int quad = lane >> 4;
    const int wbb  = (w >> 1) * 64;
    const int whh  = (w & 1) * 64;
    const int b0 = blockIdx.x * BT;
    const int h0 = blockIdx.y * BT;

    float4v acc[4][4];
#pragma unroll
    for (int i = 0; i < 4; i++)
#pragma unroll
        for (int j = 0; j < 4; j++) acc[i][j] = (float4v){0.f, 0.f, 0.f, 0.f};

    const int r0 = tid >> 3;
    const int c4 = tid & 7;
    const float* xrow = x + (size_t)(b0 + r0) * NI + 4 * c4;
    const float* wrow = W1 + (size_t)(h0 + r0) * NI + 4 * c4;

    for (int kt = 0; kt < NTILES; kt++) {
        const int ko = kt * BK;
        float4v vx[4], vw[4];
#pragma unroll
        for (int p = 0; p < 4; p++) {
            vx[p] = *(const float4v*)(xrow + (size_t)(32 * p) * NI + ko);
            vw[p] = *(const float4v*)(wrow + (size_t)(32 * p) * NI + ko);
        }
        __syncthreads();
#pragma unroll
        for (int p = 0; p < 4; p++) {
            const int row = r0 + 32 * p;
            half4 hx, lx, hw, lw;
#pragma unroll
            for (int q = 0; q < 4; q++) {
                float v = vx[p][q];
                _Float16 h = (_Float16)v;
                hx[q] = h;
                lx[q] = (_Float16)(v - (float)h);
                v = vw[p][q];
                h = (_Float16)v;
                hw[q] = h;
                lw[q] = (_Float16)(v - (float)h);
            }
            *(half4*)&xh[row * RW + 4 * c4] = hx;
            *(half4*)&xl[row * RW + 4 * c4] = lx;
            *(half4*)&wh[row * RW + 4 * c4] = hw;
            *(half4*)&wl[row * RW + 4 * c4] = lw;
        }
        __syncthreads();

        half8 ah[4], al[4];
#pragma unroll
        for (int i = 0; i < 4; i++) {
            ah[i] = *(const half8*)&xh[(wbb + 16 * i + col) * RW + 8 * quad];
            al[i] = *(const half8*)&xl[(wbb + 16 * i + col) * RW + 8 * quad];
        }
#pragma unroll
        for (int j = 0; j < 4; j++) {
            half8 bh = *(const half8*)&wh[(whh + 16 * j + col) * RW + 8 * quad];
            half8 bl = *(const half8*)&wl[(whh + 16 * j + col) * RW + 8 * quad];
#pragma unroll
            for (int i = 0; i < 4; i++) {
                acc[i][j] = __builtin_amdgcn_mfma_f32_16x16x32_f16(ah[i], bh, acc[i][j], 0, 0, 0);
                acc[i][j] = __builtin_amdgcn_mfma_f32_16x16x32_f16(ah[i], bl, acc[i][j], 0, 0, 0);
                acc[i][j] = __builtin_amdgcn_mfma_f32_16x16x32_f16(al[i], bh, acc[i][j], 0, 0, 0);
            }
        }
    }

    __syncthreads();
    float* bpl = (float*)lds;
    for (int n = tid; n < NSTEPS * 128; n += 256)
        bpl[n] = bp[(n >> 7) * NH + h0 + (n & 127)];
    __syncthreads();

    float part[16];
#pragma unroll
    for (int e = 0; e < 16; e++) part[e] = 0.f;
#pragma unroll
    for (int j = 0; j < 4; j++) {
        const int hl = whh + 16 * j + col;
        const int h = h0 + hl;
        const float w2 = W2[h];
        const float bj = b1[h];
        float x1[16];
        int cnt[16];
#pragma unroll
        for (int e = 0; e < 16; e++) {
            x1[e] = acc[e >> 2][j][e & 3] + bj;
            cnt[e] = 0;
        }
#pragma unroll
        for (int k = 0; k < NSTEPS; k++) {
            const float c = bpl[k * 128 + hl];
#pragma unroll
            for (int e = 0; e < 16; e++) cnt[e] += (x1[e] >= c) ? 1 : 0;
        }
#pragma unroll
        for (int e = 0; e < 16; e++)
            part[e] = fmaf((float)cnt[e], w2, part[e]);
    }

    __syncthreads();
    float* red = (float*)lds;
#pragma unroll
    for (int e = 0; e < 16; e++) {
        const int row = wbb + 16 * (e >> 2) + 4 * quad + (e & 3);
        red[row * 33 + (w & 1) * 16 + col] = part[e];
    }
    __syncthreads();
    if (tid < BT) {
        float s = 0.f;
#pragma unroll
        for (int c = 0; c < 32; c++) s += red[tid * 33 + c];
        atomicAdd(&out[b0 + tid], s);
    }
}

extern "C" void kernel_launch(void* const* d_in, const int* in_sizes, int n_in,
                              void* d_out, int out_size, void* d_ws, size_t ws_size,
                              hipStream_t stream) {
    const float* x    = (const float*)d_in[0];
    const float* W1   = (const float*)d_in[1];
    const float* b1   = (const float*)d_in[2];
    const float* W2   = (const float*)d_in[3];
    const float* b2   = (const float*)d_in[4];
    const float* beta = (const float*)d_in[5];
    const float* thr  = (const float*)d_in[6];
    float* out = (float*)d_out;

    const int B = in_sizes[0] / NI;  // 32768

    // ws layout: bp (NH*32 floats) | wh | wl | xh
    char* ws = (char*)d_ws;
    float*     bp  = (float*)ws;
    size_t off = (size_t)NH * 32 * 4;                // 131072
    _Float16* whp = (_Float16*)(ws + off);  off += (size_t)NH * NI * 2;
    _Float16* wlp = (_Float16*)(ws + off);  off += (size_t)NH * NI * 2;
    _Float16* xhp = (_Float16*)(ws + off);  off += (size_t)B * NI * 2;
    const size_t ws_need = off;

    if (ws_size >= ws_need) {
        const int nblk = B / 8 + 128 + 100 + (B + 255) / 256;
        snn_prep<<<nblk, 256, 0, stream>>>(x, W1, thr, beta, b1, b2, out,
                                           bp, whp, wlp, xhp, B);
        dim3 grid(B / BT, NH / BT);
        snn_main_fast<<<grid, 256, 0, stream>>>(xhp, whp, wlp, W2, bp, out);
    } else {
        snn_prep_small<<<100 + (B + 255) / 256, 256, 0, stream>>>(thr, beta, b2, out, bp, B);
        dim3 grid(B / BT, NH / BT);
        snn_main_fb<<<grid, 256, 0, stream>>>(x, W1, b1, W2, bp, out);
    }
}